// Round 1
// baseline (1180.651 us; speedup 1.0000x reference)
//
#include <hip/hip_runtime.h>

// 2-layer GCN: out = (A_norm @ relu(A_norm @ (x@W1) + b1)) @ W2 + b2
// A_norm includes self-loops; norm = dinv[src]*dinv[dst], dinv = rsqrt(deg).
//
// Workspace layout (floats), 16-float aligned header for the dtype flag:
//   [0]            : int flag, 1 = edge_index is int64, 0 = int32
//   [16 .. 16+n)   : deg -> dinv (in place)
//   h1  : n*64
//   agg1: n*64
//   h2  : n*32

constexpr int C1 = 64;
constexpr int C2 = 32;
constexpr int K1 = 768;

// ---------- edge dtype detection (device-side, graph-capture safe) ----------
__global__ void detect_k(const int* __restrict__ ei32, int* flag, int n_words) {
    __shared__ int any_nz;
    if (threadIdx.x == 0) any_nz = 0;
    __syncthreads();
    int t = threadIdx.x;
    int w = 2 * t + 1;               // odd words = high halves if int64
    if (w < n_words && ei32[w] != 0) atomicOr(&any_nz, 1);
    __syncthreads();
    if (threadIdx.x == 0) *flag = (any_nz == 0) ? 1 : 0;   // all-zero highs -> int64
}

__device__ __forceinline__ int load_idx(const void* ei, size_t pos, int m64) {
    if (m64) return (int)((const long long*)ei)[pos];
    return ((const int*)ei)[pos];
}

// ---------- degree / dinv ----------
__global__ void deg_init_k(float* deg, int n) {
    int i = blockIdx.x * 256 + threadIdx.x;
    if (i < n) deg[i] = 1.0f;        // self-loop contribution
}

__global__ void deg_count_k(const void* __restrict__ ei, const int* __restrict__ flag,
                            float* deg, int E) {
    int e = blockIdx.x * 256 + threadIdx.x;
    if (e >= E) return;
    int m64 = *flag;
    int d = load_idx(ei, (size_t)E + e, m64);   // dst
    atomicAdd(&deg[d], 1.0f);
}

__global__ void dinv_k(float* deg, int n) {
    int i = blockIdx.x * 256 + threadIdx.x;
    if (i < n) deg[i] = rsqrtf(deg[i]);         // deg >= 1 always (self-loops)
}

// ---------- GEMM1: h1[n,64] = x[n,768] @ W1[768,64], fp32 vector ----------
__global__ __launch_bounds__(256) void gemm1_k(const float* __restrict__ x,
                                               const float* __restrict__ W,
                                               float* __restrict__ h, int n) {
    __shared__ float As[32][64];   // [k][row], transposed x tile
    __shared__ float Bs[32][64];   // [k][col]
    const int tid = threadIdx.x;
    const int block_row = blockIdx.x * 64;
    const int tr = tid >> 4;       // 0..15, rows 4*tr..4*tr+3
    const int tc = tid & 15;       // 0..15, cols 4*tc..4*tc+3

    float acc[4][4] = {};

    for (int k0 = 0; k0 < K1; k0 += 32) {
        // stage A: 64 rows x 32 k = 512 float4, 2 per thread
        #pragma unroll
        for (int i = 0; i < 2; ++i) {
            int f = tid + i * 256;           // 0..511
            int row = f >> 3;                // 0..63
            int k4  = (f & 7) << 2;          // 0,4,...,28
            int grow = block_row + row;
            float4 v = make_float4(0.f, 0.f, 0.f, 0.f);
            if (grow < n) v = *(const float4*)(x + (size_t)grow * K1 + k0 + k4);
            As[k4 + 0][row] = v.x; As[k4 + 1][row] = v.y;
            As[k4 + 2][row] = v.z; As[k4 + 3][row] = v.w;
        }
        // stage B: 32 k x 64 cols = 512 float4, 2 per thread
        #pragma unroll
        for (int i = 0; i < 2; ++i) {
            int f = tid + i * 256;
            int kr = f >> 4;                 // 0..31
            int c4 = (f & 15) << 2;          // 0..60
            *(float4*)&Bs[kr][c4] = *(const float4*)(W + (size_t)(k0 + kr) * C1 + c4);
        }
        __syncthreads();
        #pragma unroll
        for (int kk = 0; kk < 32; ++kk) {
            float4 a = *(float4*)&As[kk][tr << 2];
            float4 b = *(float4*)&Bs[kk][tc << 2];
            acc[0][0] += a.x * b.x; acc[0][1] += a.x * b.y; acc[0][2] += a.x * b.z; acc[0][3] += a.x * b.w;
            acc[1][0] += a.y * b.x; acc[1][1] += a.y * b.y; acc[1][2] += a.y * b.z; acc[1][3] += a.y * b.w;
            acc[2][0] += a.z * b.x; acc[2][1] += a.z * b.y; acc[2][2] += a.z * b.z; acc[2][3] += a.z * b.w;
            acc[3][0] += a.w * b.x; acc[3][1] += a.w * b.y; acc[3][2] += a.w * b.z; acc[3][3] += a.w * b.w;
        }
        __syncthreads();
    }
    #pragma unroll
    for (int i = 0; i < 4; ++i) {
        int grow = block_row + (tr << 2) + i;
        if (grow < n)
            *(float4*)(h + (size_t)grow * C1 + (tc << 2)) =
                make_float4(acc[i][0], acc[i][1], acc[i][2], acc[i][3]);
    }
}

// ---------- layer-1 aggregation ----------
// init: agg1[v,c] = b1[c] + h1[v,c]*dinv[v]^2  (self-loop + bias)
__global__ void agg1_init_k(const float* __restrict__ h1, const float* __restrict__ dinv,
                            const float* __restrict__ b1, float* __restrict__ agg1, int n) {
    int i = blockIdx.x * 256 + threadIdx.x;
    if (i >= n * C1) return;
    int v = i >> 6, c = i & 63;
    float di = dinv[v];
    agg1[i] = b1[c] + h1[i] * di * di;
}

// one wave per edge, lane = channel (coalesced 256B gather + 256B atomic burst)
__global__ __launch_bounds__(256) void scatter1_k(const void* __restrict__ ei,
                                                  const int* __restrict__ flag,
                                                  const float* __restrict__ dinv,
                                                  const float* __restrict__ h1,
                                                  float* __restrict__ agg1, int E) {
    int e = blockIdx.x * 4 + (threadIdx.x >> 6);
    int c = threadIdx.x & 63;
    if (e >= E) return;
    int m64 = *flag;
    int s = load_idx(ei, e, m64);
    int d = load_idx(ei, (size_t)E + e, m64);
    float w = dinv[s] * dinv[d];
    atomicAdd(&agg1[(size_t)d * C1 + c], h1[(size_t)s * C1 + c] * w);
}

// ---------- GEMM2: h2[n,32] = relu(agg1)[n,64] @ W2[64,32] ----------
__global__ __launch_bounds__(256) void gemm2_k(const float* __restrict__ a,
                                               const float* __restrict__ W,
                                               float* __restrict__ h2, int n) {
    __shared__ float sW[C1 * C2];   // 64*32 = 2048 floats
    __shared__ float sR[8 * C1];    // 8 rows x 64
    const int tid = threadIdx.x;
    const int base = blockIdx.x * 8;
    #pragma unroll
    for (int i = 0; i < 2; ++i) {
        int f = tid + i * 256;      // 0..511 float4s
        *(float4*)&sW[f * 4] = *(const float4*)&W[f * 4];
    }
    #pragma unroll
    for (int i = 0; i < 2; ++i) {
        int f = tid + i * 256;      // 0..511 floats
        int r = f >> 6, c = f & 63;
        int grow = base + r;
        float v = 0.f;
        if (grow < n) v = a[(size_t)grow * C1 + c];
        sR[f] = fmaxf(v, 0.f);      // fused relu
    }
    __syncthreads();
    int r = tid >> 5, j = tid & 31;
    float acc = 0.f;
    #pragma unroll
    for (int c = 0; c < C1; ++c) acc += sR[r * C1 + c] * sW[c * C2 + j];
    int grow = base + r;
    if (grow < n) h2[(size_t)grow * C2 + j] = acc;
}

// ---------- layer-2 aggregation (straight into d_out) ----------
__global__ void out_init_k(const float* __restrict__ h2, const float* __restrict__ dinv,
                           const float* __restrict__ b2, float* __restrict__ out, int n) {
    int i = blockIdx.x * 256 + threadIdx.x;
    if (i >= n * C2) return;
    int v = i >> 5, c = i & 31;
    float di = dinv[v];
    out[i] = b2[c] + h2[i] * di * di;
}

// 2 edges per wave, 32 lanes each
__global__ __launch_bounds__(256) void scatter2_k(const void* __restrict__ ei,
                                                  const int* __restrict__ flag,
                                                  const float* __restrict__ dinv,
                                                  const float* __restrict__ h2,
                                                  float* __restrict__ out, int E) {
    int sub = threadIdx.x & 63;
    int e = blockIdx.x * 8 + ((threadIdx.x >> 6) << 1) + (sub >> 5);
    int c = sub & 31;
    if (e >= E) return;
    int m64 = *flag;
    int s = load_idx(ei, e, m64);
    int d = load_idx(ei, (size_t)E + e, m64);
    float w = dinv[s] * dinv[d];
    atomicAdd(&out[(size_t)d * C2 + c], h2[(size_t)s * C2 + c] * w);
}

extern "C" void kernel_launch(void* const* d_in, const int* in_sizes, int n_in,
                              void* d_out, int out_size, void* d_ws, size_t ws_size,
                              hipStream_t stream) {
    const float* x  = (const float*)d_in[0];
    const void*  ei = d_in[1];
    const float* W1 = (const float*)d_in[2];
    const float* b1 = (const float*)d_in[3];
    const float* W2 = (const float*)d_in[4];
    const float* b2 = (const float*)d_in[5];
    float* out = (float*)d_out;

    const int n = in_sizes[0] / K1;     // 100000
    const int E = in_sizes[1] / 2;      // 1600000

    float* ws   = (float*)d_ws;
    int*   flag = (int*)ws;             // [0]
    float* dinv = ws + 16;              // n
    float* h1   = dinv + n;             // n*64
    float* agg1 = h1 + (size_t)n * C1;  // n*64
    float* h2   = agg1 + (size_t)n * C1;// n*32

    detect_k<<<1, 256, 0, stream>>>((const int*)ei, flag, in_sizes[1]);
    deg_init_k<<<(n + 255) / 256, 256, 0, stream>>>(dinv, n);
    deg_count_k<<<(E + 255) / 256, 256, 0, stream>>>(ei, flag, dinv, E);
    dinv_k<<<(n + 255) / 256, 256, 0, stream>>>(dinv, n);
    gemm1_k<<<(n + 63) / 64, 256, 0, stream>>>(x, W1, h1, n);
    agg1_init_k<<<((size_t)n * C1 + 255) / 256, 256, 0, stream>>>(h1, dinv, b1, agg1, n);
    scatter1_k<<<(E + 3) / 4, 256, 0, stream>>>(ei, flag, dinv, h1, agg1, E);
    gemm2_k<<<(n + 7) / 8, 256, 0, stream>>>(agg1, W2, h2, n);
    out_init_k<<<((size_t)n * C2 + 255) / 256, 256, 0, stream>>>(h2, dinv, b2, out, n);
    scatter2_k<<<(E + 7) / 8, 256, 0, stream>>>(ei, flag, dinv, h2, out, E);
}

// Round 2
// 819.740 us; speedup vs baseline: 1.4403x; 1.4403x over previous
//
#include <hip/hip_runtime.h>

// 2-layer GCN, gather formulation via device-built CSR:
//   dinv = rsqrt(1 + indeg)
//   g1 = dinv * (x @ W1)                      (norm folded into GEMM epilogue)
//   row(v) = relu(b1 + dinv[v]*(g1[v] + sum_{in} g1[src]))
//   g2[v] = dinv[v] * (row(v) @ W2)           (fused into gather1 kernel)
//   out[v] = b2 + dinv[v]*(g2[v] + sum_{in} g2[src])

constexpr int C1 = 64;
constexpr int C2 = 32;
constexpr int K1 = 768;
constexpr int SCAN_BS = 256;
constexpr int SCAN_ELEMS = 2048;   // 8 per thread

// ---------- edge dtype detection (device-side, graph-capture safe) ----------
__global__ void detect_k(const int* __restrict__ ei32, int* flag, int n_words) {
    __shared__ int any_nz;
    if (threadIdx.x == 0) any_nz = 0;
    __syncthreads();
    int w = 2 * threadIdx.x + 1;     // odd words = high halves if int64
    if (w < n_words && ei32[w] != 0) atomicOr(&any_nz, 1);
    __syncthreads();
    if (threadIdx.x == 0) *flag = (any_nz == 0) ? 1 : 0;
}

__device__ __forceinline__ int load_idx(const void* ei, size_t pos, int m64) {
    if (m64) return (int)((const long long*)ei)[pos];
    return ((const int*)ei)[pos];
}

// ---------- degree ----------
__global__ void zero_k(int* p, int n) {
    int i = blockIdx.x * 256 + threadIdx.x;
    if (i < n) p[i] = 0;
}

__global__ void cnt_k(const void* __restrict__ ei, const int* __restrict__ flag,
                      int* cnt, int E) {
    int e = blockIdx.x * 256 + threadIdx.x;
    if (e >= E) return;
    int m64 = *flag;
    int d = load_idx(ei, (size_t)E + e, m64);
    atomicAdd(&cnt[d], 1);
}

__global__ void dinv_k(const int* __restrict__ cnt, float* dinv, int n) {
    int i = blockIdx.x * 256 + threadIdx.x;
    if (i < n) dinv[i] = rsqrtf(1.0f + (float)cnt[i]);   // +1 self-loop
}

// ---------- block scan (exclusive) over cnt -> offsets, cursor ----------
__global__ void scan1_k(const int* __restrict__ cnt, int* partials, int n) {
    __shared__ int s[SCAN_BS];
    int base = blockIdx.x * SCAN_ELEMS;
    int t = threadIdx.x;
    int sum = 0;
    #pragma unroll
    for (int i = 0; i < 8; ++i) {
        int idx = base + t * 8 + i;
        if (idx < n) sum += cnt[idx];
    }
    s[t] = sum;
    __syncthreads();
    for (int off = 128; off > 0; off >>= 1) {
        if (t < off) s[t] += s[t + off];
        __syncthreads();
    }
    if (t == 0) partials[blockIdx.x] = s[0];
}

__global__ void scan2_k(int* partials, int* total_out, int nb) {
    __shared__ int s[256];
    int t = threadIdx.x;
    int v = (t < nb) ? partials[t] : 0;
    s[t] = v;
    __syncthreads();
    for (int off = 1; off < 256; off <<= 1) {
        int add = (t >= off) ? s[t - off] : 0;
        __syncthreads();
        s[t] += add;
        __syncthreads();
    }
    if (t < nb) partials[t] = s[t] - v;     // exclusive block offsets
    if (t == 0) *total_out = s[255];        // offsets[n]
}

__global__ void scan3_k(const int* __restrict__ cnt, const int* __restrict__ partials,
                        int* offsets, int* cursor, int n) {
    __shared__ int s[SCAN_BS];
    int base = blockIdx.x * SCAN_ELEMS;
    int t = threadIdx.x;
    int local[8];
    int sum = 0;
    #pragma unroll
    for (int i = 0; i < 8; ++i) {
        int idx = base + t * 8 + i;
        int v = (idx < n) ? cnt[idx] : 0;
        local[i] = sum;
        sum += v;
    }
    int mine = sum;
    s[t] = sum;
    __syncthreads();
    for (int off = 1; off < 256; off <<= 1) {
        int add = (t >= off) ? s[t - off] : 0;
        __syncthreads();
        s[t] += add;
        __syncthreads();
    }
    int texcl = s[t] - mine;
    int boff = partials[blockIdx.x];
    #pragma unroll
    for (int i = 0; i < 8; ++i) {
        int idx = base + t * 8 + i;
        if (idx < n) {
            int o = boff + texcl + local[i];
            offsets[idx] = o;
            cursor[idx] = o;
        }
    }
}

// ---------- CSR fill ----------
__global__ void fill_k(const void* __restrict__ ei, const int* __restrict__ flag,
                       int* cursor, int* adj, int E) {
    int e = blockIdx.x * 256 + threadIdx.x;
    if (e >= E) return;
    int m64 = *flag;
    int s = load_idx(ei, e, m64);
    int d = load_idx(ei, (size_t)E + e, m64);
    int pos = atomicAdd(&cursor[d], 1);
    adj[pos] = s;
}

// ---------- GEMM1: g1[n,64] = dinv * (x[n,768] @ W1[768,64]) ----------
__global__ __launch_bounds__(256) void gemm1_k(const float* __restrict__ x,
                                               const float* __restrict__ W,
                                               const float* __restrict__ dinv,
                                               float* __restrict__ g1, int n) {
    __shared__ float As[32][64];   // [k][row]
    __shared__ float Bs[32][64];   // [k][col]
    const int tid = threadIdx.x;
    const int block_row = blockIdx.x * 64;
    const int tr = tid >> 4;
    const int tc = tid & 15;

    float acc[4][4] = {};

    for (int k0 = 0; k0 < K1; k0 += 32) {
        #pragma unroll
        for (int i = 0; i < 2; ++i) {
            int f = tid + i * 256;
            int row = f >> 3;
            int k4 = (f & 7) << 2;
            int grow = block_row + row;
            float4 v = make_float4(0.f, 0.f, 0.f, 0.f);
            if (grow < n) v = *(const float4*)(x + (size_t)grow * K1 + k0 + k4);
            As[k4 + 0][row] = v.x; As[k4 + 1][row] = v.y;
            As[k4 + 2][row] = v.z; As[k4 + 3][row] = v.w;
        }
        #pragma unroll
        for (int i = 0; i < 2; ++i) {
            int f = tid + i * 256;
            int kr = f >> 4;
            int c4 = (f & 15) << 2;
            *(float4*)&Bs[kr][c4] = *(const float4*)(W + (size_t)(k0 + kr) * C1 + c4);
        }
        __syncthreads();
        #pragma unroll
        for (int kk = 0; kk < 32; ++kk) {
            float4 a = *(float4*)&As[kk][tr << 2];
            float4 b = *(float4*)&Bs[kk][tc << 2];
            acc[0][0] += a.x * b.x; acc[0][1] += a.x * b.y; acc[0][2] += a.x * b.z; acc[0][3] += a.x * b.w;
            acc[1][0] += a.y * b.x; acc[1][1] += a.y * b.y; acc[1][2] += a.y * b.z; acc[1][3] += a.y * b.w;
            acc[2][0] += a.z * b.x; acc[2][1] += a.z * b.y; acc[2][2] += a.z * b.z; acc[2][3] += a.z * b.w;
            acc[3][0] += a.w * b.x; acc[3][1] += a.w * b.y; acc[3][2] += a.w * b.z; acc[3][3] += a.w * b.w;
        }
        __syncthreads();
    }
    #pragma unroll
    for (int i = 0; i < 4; ++i) {
        int grow = block_row + (tr << 2) + i;
        if (grow < n) {
            float dv = dinv[grow];
            *(float4*)(g1 + (size_t)grow * C1 + (tc << 2)) =
                make_float4(acc[i][0] * dv, acc[i][1] * dv, acc[i][2] * dv, acc[i][3] * dv);
        }
    }
}

// ---------- layer-1 gather + fused GEMM2 ----------
// one wave per node (lane = channel). After gathering the 64-wide row,
// the wave computes h2 = relu(row)@W2 via LDS and writes g2 = dinv*h2.
__global__ __launch_bounds__(256) void gather1_k(const int* __restrict__ offsets,
                                                 const int* __restrict__ adj,
                                                 const float* __restrict__ dinv,
                                                 const float* __restrict__ g1,
                                                 const float* __restrict__ b1,
                                                 const float* __restrict__ W2,
                                                 float* __restrict__ g2, int n) {
    __shared__ float sW[C1 * C2];    // 8 KB
    __shared__ float srow[4][C1];
    const int tid = threadIdx.x;
    for (int i = tid; i < C1 * C2; i += 256) sW[i] = W2[i];

    const int wid = tid >> 6;
    const int c = tid & 63;
    const int v = blockIdx.x * 4 + wid;

    float r = 0.f;
    float dv = 0.f;
    if (v < n) {
        dv = dinv[v];
        int start = offsets[v], end = offsets[v + 1];
        float acc = g1[(size_t)v * C1 + c];          // self-loop term
        int j = start;
        for (; j + 4 <= end; j += 4) {
            int s0 = adj[j], s1 = adj[j + 1], s2 = adj[j + 2], s3 = adj[j + 3];
            float a0 = g1[(size_t)s0 * C1 + c];
            float a1 = g1[(size_t)s1 * C1 + c];
            float a2 = g1[(size_t)s2 * C1 + c];
            float a3 = g1[(size_t)s3 * C1 + c];
            acc += (a0 + a1) + (a2 + a3);
        }
        for (; j < end; ++j) acc += g1[(size_t)adj[j] * C1 + c];
        r = fmaxf(b1[c] + dv * acc, 0.f);            // fused bias + relu
    }
    srow[wid][c] = r;
    __syncthreads();                                  // covers sW + srow

    if (v < n && c < C2) {
        float acc = 0.f;
        #pragma unroll
        for (int k = 0; k < C1; ++k) acc += srow[wid][k] * sW[k * C2 + c];
        g2[(size_t)v * C2 + c] = dv * acc;
    }
}

// ---------- layer-2 gather (2 nodes per wave, 32 lanes each) ----------
__global__ __launch_bounds__(256) void gather2_k(const int* __restrict__ offsets,
                                                 const int* __restrict__ adj,
                                                 const float* __restrict__ dinv,
                                                 const float* __restrict__ g2,
                                                 const float* __restrict__ b2,
                                                 float* __restrict__ out, int n) {
    int v = blockIdx.x * 8 + (threadIdx.x >> 5);
    int c = threadIdx.x & 31;
    if (v >= n) return;
    int start = offsets[v], end = offsets[v + 1];
    float acc = g2[(size_t)v * C2 + c];              // self-loop term
    int j = start;
    for (; j + 4 <= end; j += 4) {
        int s0 = adj[j], s1 = adj[j + 1], s2 = adj[j + 2], s3 = adj[j + 3];
        float a0 = g2[(size_t)s0 * C2 + c];
        float a1 = g2[(size_t)s1 * C2 + c];
        float a2 = g2[(size_t)s2 * C2 + c];
        float a3 = g2[(size_t)s3 * C2 + c];
        acc += (a0 + a1) + (a2 + a3);
    }
    for (; j < end; ++j) acc += g2[(size_t)adj[j] * C2 + c];
    out[(size_t)v * C2 + c] = b2[c] + dinv[v] * acc;
}

extern "C" void kernel_launch(void* const* d_in, const int* in_sizes, int n_in,
                              void* d_out, int out_size, void* d_ws, size_t ws_size,
                              hipStream_t stream) {
    const float* x  = (const float*)d_in[0];
    const void*  ei = d_in[1];
    const float* W1 = (const float*)d_in[2];
    const float* b1 = (const float*)d_in[3];
    const float* W2 = (const float*)d_in[4];
    const float* b2 = (const float*)d_in[5];
    float* out = (float*)d_out;

    const int n = in_sizes[0] / K1;     // 100000
    const int E = in_sizes[1] / 2;      // 1600000

    // workspace layout (all 4-byte types)
    float* ws      = (float*)d_ws;
    int*   flag    = (int*)ws;                      // 16-float header
    float* dinv    = ws + 16;                       // n
    float* g1      = dinv + n;                      // n*64
    float* g2      = g1 + (size_t)n * C1;           // n*32
    int*   cnt     = (int*)(g2 + (size_t)n * C2);   // n
    int*   offsets = cnt + n;                       // n+1
    int*   cursor  = offsets + n + 1;               // n
    int*   partials= cursor + n;                    // 256 (padded)
    int*   adj     = partials + 256;                // E
    // total ~ (16 + 97n) + (3n + 257 + E) words  ≈ 58.4 MB for n=1e5, E=1.6e6

    const int nb_scan = (n + SCAN_ELEMS - 1) / SCAN_ELEMS;   // 49

    detect_k<<<1, 256, 0, stream>>>((const int*)ei, flag, in_sizes[1]);
    zero_k<<<(n + 255) / 256, 256, 0, stream>>>(cnt, n);
    cnt_k<<<(E + 255) / 256, 256, 0, stream>>>(ei, flag, cnt, E);
    dinv_k<<<(n + 255) / 256, 256, 0, stream>>>(cnt, dinv, n);

    gemm1_k<<<(n + 63) / 64, 256, 0, stream>>>(x, W1, dinv, g1, n);

    scan1_k<<<nb_scan, SCAN_BS, 0, stream>>>(cnt, partials, n);
    scan2_k<<<1, 256, 0, stream>>>(partials, offsets + n, nb_scan);
    scan3_k<<<nb_scan, SCAN_BS, 0, stream>>>(cnt, partials, offsets, cursor, n);
    fill_k<<<(E + 255) / 256, 256, 0, stream>>>(ei, flag, cursor, adj, E);

    gather1_k<<<(n + 3) / 4, 256, 0, stream>>>(offsets, adj, dinv, g1, b1, W2, g2, n);
    gather2_k<<<(n + 7) / 8, 256, 0, stream>>>(offsets, adj, dinv, g2, b2, out, n);
}